// Round 2
// baseline (319.317 us; speedup 1.0000x reference)
//
#include <hip/hip_runtime.h>
#include <hip/hip_bf16.h>
#include <math.h>

// n = 8192 (power of two) for this problem.
#define SORT_N 8192
#define ROW_BLOCK 256

// ---------------------------------------------------------------------------
// Kernel 1: compute e_i = log(dur_i + 1e-32) - theta_i, then bitonic argsort
// in LDS (single block). Outputs e_sorted and perm.
// ---------------------------------------------------------------------------
__global__ __launch_bounds__(1024) void bitonic_argsort_kernel(
    const float* __restrict__ theta, const float* __restrict__ dur,
    float* __restrict__ e_sorted, int* __restrict__ perm, int n) {
  __shared__ float key[SORT_N];
  __shared__ int   val[SORT_N];

  for (int i = threadIdx.x; i < n; i += blockDim.x) {
    key[i] = logf(dur[i] + 1e-32f) - theta[i];
    val[i] = i;
  }
  __syncthreads();

  for (int k = 2; k <= n; k <<= 1) {
    for (int j = k >> 1; j > 0; j >>= 1) {
      for (int i = threadIdx.x; i < n; i += blockDim.x) {
        int ixj = i ^ j;
        if (ixj > i) {
          bool up = ((i & k) == 0);
          float a = key[i], b = key[ixj];
          if ((a > b) == up) {
            key[i] = b; key[ixj] = a;
            int t = val[i]; val[i] = val[ixj]; val[ixj] = t;
          }
        }
      }
      __syncthreads();
    }
  }

  for (int i = threadIdx.x; i < n; i += blockDim.x) {
    e_sorted[i] = key[i];
    perm[i] = val[i];
  }
}

// inv[perm[i]] = i
__global__ void scatter_inv_kernel(const int* __restrict__ perm,
                                   int* __restrict__ inv, int n) {
  int i = blockIdx.x * blockDim.x + threadIdx.x;
  if (i < n) inv[perm[i]] = i;
}

// ev_s[i] = events[inv[i]], th_s[i] = theta[inv[i]]
__global__ void gather_side_kernel(const int* __restrict__ inv,
                                   const int* __restrict__ events,
                                   const float* __restrict__ theta,
                                   float* __restrict__ ev_s,
                                   float* __restrict__ th_s, int n) {
  int i = blockIdx.x * blockDim.x + threadIdx.x;
  if (i < n) {
    int k = inv[i];
    ev_s[i] = (float)events[k];
    th_s[i] = theta[k];
  }
}

// ---------------------------------------------------------------------------
// Main O(n^2) kernel: one block per sorted row i.
// condE_i = (1/(n*sqrt(2*pi))) * sum_j exp(-0.5 d^2) * ev_s[j]  + n*1e-32
// surv_i  = (1/n) * sum_j 0.5*(1+erf(d/sqrt(2)))
// atomicAdd(out, -(log condE - log surv + th_s[i]) * ev_s[i] / n)
// ---------------------------------------------------------------------------
__global__ __launch_bounds__(ROW_BLOCK) void row_kernel(
    const float* __restrict__ es, const float* __restrict__ ev_s,
    const float* __restrict__ th_s, float* __restrict__ out, int n) {
  const int i = blockIdx.x;
  const float ei = es[i];
  const float inv_sqrt2 = 0.70710678118654752f;

  float sumE = 0.0f, sumS = 0.0f;
  for (int j = threadIdx.x; j < n; j += ROW_BLOCK) {
    float d = ei - es[j];
    sumE = fmaf(__expf(-0.5f * d * d), ev_s[j], sumE);
    sumS += 0.5f + 0.5f * erff(d * inv_sqrt2);
  }

  // wave (64-lane) reduction
  #pragma unroll
  for (int off = 32; off > 0; off >>= 1) {
    sumE += __shfl_down(sumE, off, 64);
    sumS += __shfl_down(sumS, off, 64);
  }

  __shared__ float sE[ROW_BLOCK / 64], sS[ROW_BLOCK / 64];
  const int wave = threadIdx.x >> 6;
  const int lane = threadIdx.x & 63;
  if (lane == 0) { sE[wave] = sumE; sS[wave] = sumS; }
  __syncthreads();

  if (threadIdx.x == 0) {
    float tE = 0.0f, tS = 0.0f;
    #pragma unroll
    for (int w = 0; w < ROW_BLOCK / 64; ++w) { tE += sE[w]; tS += sS[w]; }
    const float fn = (float)n;
    const float inv_sqrt_2pi = 0.39894228040143267794f;  // 1/sqrt(2*pi)
    float condE = tE * inv_sqrt_2pi / fn + fn * 1e-32f;
    float surv  = tS / fn;
    float term = (logf(condE) - logf(surv) + th_s[i]) * ev_s[i];
    atomicAdd(out, -term / fn);
  }
}

extern "C" void kernel_launch(void* const* d_in, const int* in_sizes, int n_in,
                              void* d_out, int out_size, void* d_ws, size_t ws_size,
                              hipStream_t stream) {
  const float* theta = (const float*)d_in[0];   // log_h, (n,1) fp32
  const float* dur   = (const float*)d_in[1];   // durations, (n,) fp32
  const int*   ev    = (const int*)d_in[2];     // events, (n,) int32
  float* out = (float*)d_out;
  const int n = in_sizes[1];

  // workspace layout
  char* ws = (char*)d_ws;
  float* e_sorted = (float*)ws;                       ws += n * sizeof(float);
  int*   perm     = (int*)ws;                         ws += n * sizeof(int);
  int*   inv      = (int*)ws;                         ws += n * sizeof(int);
  float* ev_s     = (float*)ws;                       ws += n * sizeof(float);
  float* th_s     = (float*)ws;                       ws += n * sizeof(float);

  hipMemsetAsync(d_out, 0, out_size * sizeof(float), stream);

  bitonic_argsort_kernel<<<1, 1024, 0, stream>>>(theta, dur, e_sorted, perm, n);
  scatter_inv_kernel<<<(n + 255) / 256, 256, 0, stream>>>(perm, inv, n);
  gather_side_kernel<<<(n + 255) / 256, 256, 0, stream>>>(inv, ev, theta, ev_s, th_s, n);
  row_kernel<<<n, ROW_BLOCK, 0, stream>>>(e_sorted, ev_s, th_s, out, n);
}

// Round 3
// 140.205 us; speedup vs baseline: 2.2775x; 2.2775x over previous
//
#include <hip/hip_runtime.h>
#include <math.h>
#include <stdint.h>

#define RB 256      // block size (all kernels)
#define ROWS 8      // rows per block in row_kernel

// float -> orderable uint32 (ascending), packed with index for stable unique keys
__device__ __forceinline__ uint64_t order_key(float f, int idx) {
  uint32_t u = __float_as_uint(f);
  u = (u & 0x80000000u) ? ~u : (u | 0x80000000u);
  return ((uint64_t)u << 32) | (uint32_t)idx;
}

// e_i = log(dur_i + 1e-32) - theta_i ; build sort keys; zero rank
__global__ void prep_kernel(const float* __restrict__ theta,
                            const float* __restrict__ dur,
                            float* __restrict__ e, uint64_t* __restrict__ key,
                            int* __restrict__ rank, int n) {
  int i = blockIdx.x * blockDim.x + threadIdx.x;
  if (i < n) {
    float ei = logf(dur[i] + 1e-32f) - theta[i];
    e[i] = ei;
    key[i] = order_key(ei, i);
    rank[i] = 0;
  }
}

// rank[i] += #{j in chunk : key[j] < key[i]}   (counting-rank argsort)
// j is block-uniform -> compiler emits scalar loads for key[jbase+jj]
__global__ __launch_bounds__(RB) void rank_kernel(
    const uint64_t* __restrict__ key, int* __restrict__ rank, int n) {
  int i = blockIdx.x * RB + threadIdx.x;
  uint64_t ki = key[i];
  int jchunk = n >> 3;                  // gridDim.y == 8
  int jbase = blockIdx.y * jchunk;
  int cnt = 0;
  #pragma unroll 8
  for (int jj = 0; jj < jchunk; ++jj) {
    cnt += (key[jbase + jj] < ki) ? 1 : 0;
  }
  atomicAdd(&rank[i], cnt);
}

// rank[k] == inv[k] (sorted position of element k). Build:
//   pe[rank[k]].x = e[k]            (e_sorted scatter)
//   pe[k].y      = ev[rank[k]]      (reference's inverse-perm side reorder)
//   th_s[k]      = theta[rank[k]]
__global__ void scatter_kernel(const float* __restrict__ e,
                               const int* __restrict__ rank,
                               const int* __restrict__ ev,
                               const float* __restrict__ theta,
                               float2* __restrict__ pe,
                               float* __restrict__ th_s, int n) {
  int k = blockIdx.x * blockDim.x + threadIdx.x;
  if (k < n) {
    int r = rank[k];
    ((float*)&pe[r])[0] = e[k];          // .x — scatter (distinct dword, no race)
    ((float*)&pe[k])[1] = (float)ev[r];  // .y — gather
    th_s[k] = theta[r];
  }
}

// ---------------------------------------------------------------------------
// Main O(n^2) kernel: ROWS rows per block.
// pdf = exp(-d^2/2); cdf via A&S 7.1.26 erf which REUSES the same exp:
//   erf(x) = 1 - poly(t)*exp(-x^2), t = 1/(1+p x), x = |d|/sqrt(2)
// ---------------------------------------------------------------------------
__global__ __launch_bounds__(RB) void row_kernel(
    const float2* __restrict__ pe, const float* __restrict__ th_s,
    float* __restrict__ out, int n) {
  const int row0 = blockIdx.x * ROWS;

  float ei[ROWS], sumE[ROWS], sc[ROWS];
  #pragma unroll
  for (int r = 0; r < ROWS; ++r) {
    ei[r] = pe[row0 + r].x;     // block-uniform -> scalar load
    sumE[r] = 0.0f;
    sc[r] = 0.0f;
  }

  const float P2 = 0.23164390f;  // 0.3275911 * (1/sqrt(2))

  for (int j = threadIdx.x; j < n; j += RB) {
    float2 q = pe[j];
    float ej = q.x, evj = q.y;
    #pragma unroll
    for (int r = 0; r < ROWS; ++r) {
      float d = ei[r] - ej;
      float g = __expf(-0.5f * d * d);          // shared by pdf and erf
      sumE[r] = fmaf(g, evj, sumE[r]);
      float t = __builtin_amdgcn_rcpf(fmaf(P2, __builtin_fabsf(d), 1.0f));
      float poly = t * (0.254829592f +
                   t * (-0.284496736f +
                   t * (1.421413741f +
                   t * (-1.453152027f +
                   t * 1.061405429f))));
      float erfa = fmaf(-poly, g, 1.0f);        // erf(|x|)
      sc[r] += __builtin_copysignf(erfa, d);    // sum of sign*erf; 0.5n added later
    }
  }

  // per-wave shuffle reduction
  #pragma unroll
  for (int r = 0; r < ROWS; ++r) {
    #pragma unroll
    for (int off = 32; off > 0; off >>= 1) {
      sumE[r] += __shfl_down(sumE[r], off, 64);
      sc[r]   += __shfl_down(sc[r], off, 64);
    }
  }

  __shared__ float red[RB / 64][ROWS][2];
  const int wave = threadIdx.x >> 6;
  const int lane = threadIdx.x & 63;
  if (lane == 0) {
    #pragma unroll
    for (int r = 0; r < ROWS; ++r) {
      red[wave][r][0] = sumE[r];
      red[wave][r][1] = sc[r];
    }
  }
  __syncthreads();

  if (threadIdx.x < ROWS) {
    const int r = threadIdx.x;
    float tE = 0.0f, tS = 0.0f;
    #pragma unroll
    for (int w = 0; w < RB / 64; ++w) { tE += red[w][r][0]; tS += red[w][r][1]; }
    const float fn = (float)n;
    const float inv_sqrt_2pi = 0.39894228040143267794f;
    float condE = tE * inv_sqrt_2pi / fn + fn * 1e-32f;
    float surv  = (0.5f * fn + 0.5f * tS) / fn;   // sum cdf / n
    const int i = row0 + r;
    float evi = pe[i].y;
    float term = (__logf(condE) - __logf(surv) + th_s[i]) * evi;
    atomicAdd(out, -term / fn);
  }
}

extern "C" void kernel_launch(void* const* d_in, const int* in_sizes, int n_in,
                              void* d_out, int out_size, void* d_ws, size_t ws_size,
                              hipStream_t stream) {
  const float* theta = (const float*)d_in[0];   // log_h (n,1) fp32
  const float* dur   = (const float*)d_in[1];   // durations (n,) fp32
  const int*   ev    = (const int*)d_in[2];     // events (n,) int32
  float* out = (float*)d_out;
  const int n = in_sizes[1];

  // workspace layout (8-byte aligned first)
  char* ws = (char*)d_ws;
  uint64_t* key   = (uint64_t*)ws;  ws += n * sizeof(uint64_t);
  float2*   pe    = (float2*)ws;    ws += n * sizeof(float2);
  float*    e     = (float*)ws;     ws += n * sizeof(float);
  int*      rank  = (int*)ws;       ws += n * sizeof(int);
  float*    th_s  = (float*)ws;     ws += n * sizeof(float);

  hipMemsetAsync(d_out, 0, out_size * sizeof(float), stream);

  int nb = (n + RB - 1) / RB;
  prep_kernel<<<nb, RB, 0, stream>>>(theta, dur, e, key, rank, n);
  rank_kernel<<<dim3(n / RB, 8), RB, 0, stream>>>(key, rank, n);
  scatter_kernel<<<nb, RB, 0, stream>>>(e, rank, ev, theta, pe, th_s, n);
  row_kernel<<<n / ROWS, RB, 0, stream>>>(pe, th_s, out, n);
}

// Round 4
// 105.569 us; speedup vs baseline: 3.0247x; 1.3281x over previous
//
#include <hip/hip_runtime.h>
#include <math.h>
#include <stdint.h>

#define RB 256      // block size (all kernels)
#define ROWS 16     // rows per block in row_kernel
#define YSPLIT 32   // j-split in rank_kernel

// float -> orderable uint32 (ascending), packed with index for stable unique keys
__device__ __forceinline__ uint64_t order_key(float f, int idx) {
  uint32_t u = __float_as_uint(f);
  u = (u & 0x80000000u) ? ~u : (u | 0x80000000u);
  return ((uint64_t)u << 32) | (uint32_t)idx;
}

// e_i = log(dur_i + 1e-32) - theta_i ; build sort keys; zero rank
__global__ void prep_kernel(const float* __restrict__ theta,
                            const float* __restrict__ dur,
                            float* __restrict__ e, uint64_t* __restrict__ key,
                            int* __restrict__ rank, int n) {
  int i = blockIdx.x * blockDim.x + threadIdx.x;
  if (i < n) {
    float ei = logf(dur[i] + 1e-32f) - theta[i];
    e[i] = ei;
    key[i] = order_key(ei, i);
    rank[i] = 0;
  }
}

// rank[i] += #{j in chunk : key[j] < key[i]}   (counting-rank argsort)
// j block-uniform -> scalar s_load batches; YSPLIT*32 blocks hide latency via TLP
__global__ __launch_bounds__(RB) void rank_kernel(
    const uint64_t* __restrict__ key, int* __restrict__ rank, int n) {
  int i = blockIdx.x * RB + threadIdx.x;
  uint64_t ki = key[i];
  int jchunk = n / YSPLIT;
  int jbase = blockIdx.y * jchunk;
  int cnt = 0;
  #pragma unroll 16
  for (int jj = 0; jj < jchunk; ++jj) {
    cnt += (key[jbase + jj] < ki) ? 1 : 0;
  }
  atomicAdd(&rank[i], cnt);
}

// rank[k] == inv[k] (sorted position of element k). Build:
//   pe[rank[k]].x = e[k]            (e_sorted scatter)
//   pe[k].y      = ev[rank[k]]      (reference's inverse-perm side reorder)
//   th_s[k]      = theta[rank[k]]
__global__ void scatter_kernel(const float* __restrict__ e,
                               const int* __restrict__ rank,
                               const int* __restrict__ ev,
                               const float* __restrict__ theta,
                               float2* __restrict__ pe,
                               float* __restrict__ th_s, int n) {
  int k = blockIdx.x * blockDim.x + threadIdx.x;
  if (k < n) {
    int r = rank[k];
    ((float*)&pe[r])[0] = e[k];          // .x — scatter (distinct dword, no race)
    ((float*)&pe[k])[1] = (float)ev[r];  // .y — gather
    th_s[k] = theta[r];
  }
}

// ---------------------------------------------------------------------------
// Main O(n^2) kernel: ROWS rows per block.
// pdf = exp(-d^2/2); cdf via A&S 7.1.26 erf which REUSES the same exp:
//   erf(x) = 1 - poly(t)*exp(-x^2), t = 1/(1+p x), x = |d|/sqrt(2)
// exp & rcp ride the (underused) trans pipe; poly rides the FMA pipe.
// ---------------------------------------------------------------------------
__global__ __launch_bounds__(RB) void row_kernel(
    const float2* __restrict__ pe, const float* __restrict__ th_s,
    float* __restrict__ out, int n) {
  const int row0 = blockIdx.x * ROWS;

  float ei[ROWS], sumE[ROWS], sc[ROWS];
  #pragma unroll
  for (int r = 0; r < ROWS; ++r) {
    ei[r] = pe[row0 + r].x;     // block-uniform -> scalar load
    sumE[r] = 0.0f;
    sc[r] = 0.0f;
  }

  const float P2 = 0.23164390f;  // 0.3275911 * (1/sqrt(2))

  for (int j = threadIdx.x; j < n; j += RB) {
    float2 q = pe[j];
    float ej = q.x, evj = q.y;
    #pragma unroll
    for (int r = 0; r < ROWS; ++r) {
      float d = ei[r] - ej;
      float g = __expf(-0.5f * d * d);          // shared by pdf and erf
      sumE[r] = fmaf(g, evj, sumE[r]);
      float t = __builtin_amdgcn_rcpf(fmaf(P2, __builtin_fabsf(d), 1.0f));
      float poly = t * (0.254829592f +
                   t * (-0.284496736f +
                   t * (1.421413741f +
                   t * (-1.453152027f +
                   t * 1.061405429f))));
      float erfa = fmaf(-poly, g, 1.0f);        // erf(|x|)
      sc[r] += __builtin_copysignf(erfa, d);    // sum of sign*erf; 0.5n added later
    }
  }

  // per-wave shuffle reduction
  #pragma unroll
  for (int r = 0; r < ROWS; ++r) {
    #pragma unroll
    for (int off = 32; off > 0; off >>= 1) {
      sumE[r] += __shfl_down(sumE[r], off, 64);
      sc[r]   += __shfl_down(sc[r], off, 64);
    }
  }

  __shared__ float red[RB / 64][ROWS][2];
  const int wave = threadIdx.x >> 6;
  const int lane = threadIdx.x & 63;
  if (lane == 0) {
    #pragma unroll
    for (int r = 0; r < ROWS; ++r) {
      red[wave][r][0] = sumE[r];
      red[wave][r][1] = sc[r];
    }
  }
  __syncthreads();

  if (threadIdx.x < ROWS) {
    const int r = threadIdx.x;
    float tE = 0.0f, tS = 0.0f;
    #pragma unroll
    for (int w = 0; w < RB / 64; ++w) { tE += red[w][r][0]; tS += red[w][r][1]; }
    const float fn = (float)n;
    const float inv_sqrt_2pi = 0.39894228040143267794f;
    float condE = tE * inv_sqrt_2pi / fn + fn * 1e-32f;
    float surv  = (0.5f * fn + 0.5f * tS) / fn;   // sum cdf / n
    const int i = row0 + r;
    float evi = pe[i].y;
    float term = (__logf(condE) - __logf(surv) + th_s[i]) * evi;
    atomicAdd(out, -term / fn);
  }
}

extern "C" void kernel_launch(void* const* d_in, const int* in_sizes, int n_in,
                              void* d_out, int out_size, void* d_ws, size_t ws_size,
                              hipStream_t stream) {
  const float* theta = (const float*)d_in[0];   // log_h (n,1) fp32
  const float* dur   = (const float*)d_in[1];   // durations (n,) fp32
  const int*   ev    = (const int*)d_in[2];     // events (n,) int32
  float* out = (float*)d_out;
  const int n = in_sizes[1];

  // workspace layout (8-byte aligned first)
  char* ws = (char*)d_ws;
  uint64_t* key   = (uint64_t*)ws;  ws += n * sizeof(uint64_t);
  float2*   pe    = (float2*)ws;    ws += n * sizeof(float2);
  float*    e     = (float*)ws;     ws += n * sizeof(float);
  int*      rank  = (int*)ws;       ws += n * sizeof(int);
  float*    th_s  = (float*)ws;     ws += n * sizeof(float);

  hipMemsetAsync(d_out, 0, out_size * sizeof(float), stream);

  int nb = (n + RB - 1) / RB;
  prep_kernel<<<nb, RB, 0, stream>>>(theta, dur, e, key, rank, n);
  rank_kernel<<<dim3(n / RB, YSPLIT), RB, 0, stream>>>(key, rank, n);
  scatter_kernel<<<nb, RB, 0, stream>>>(e, rank, ev, theta, pe, th_s, n);
  row_kernel<<<n / ROWS, RB, 0, stream>>>(pe, th_s, out, n);
}

// Round 5
// 101.894 us; speedup vs baseline: 3.1338x; 1.0361x over previous
//
#include <hip/hip_runtime.h>
#include <math.h>
#include <stdint.h>

#define RB 256      // block size (all kernels)
#define ROWS 8      // rows per block in row_kernel
#define JT 512      // j-tile (keys) per block in rank_kernel

// float -> orderable uint32 (ascending), packed with index for stable unique keys
__device__ __forceinline__ uint64_t order_key(float f, int idx) {
  uint32_t u = __float_as_uint(f);
  u = (u & 0x80000000u) ? ~u : (u | 0x80000000u);
  return ((uint64_t)u << 32) | (uint32_t)idx;
}

// e_i = log(dur_i + 1e-32) - theta_i ; build sort keys; zero rank
__global__ void prep_kernel(const float* __restrict__ theta,
                            const float* __restrict__ dur,
                            float* __restrict__ e, uint64_t* __restrict__ key,
                            int* __restrict__ rank, int n) {
  int i = blockIdx.x * blockDim.x + threadIdx.x;
  if (i < n) {
    float ei = logf(dur[i] + 1e-32f) - theta[i];
    e[i] = ei;
    key[i] = order_key(ei, i);
    rank[i] = 0;
  }
}

// rank[i] += #{j in tile : key[j] < key[i]} — LDS-tiled counting-rank.
// All lanes read the same LDS address per jj -> broadcast, conflict-free.
__global__ __launch_bounds__(RB) void rank_kernel(
    const uint64_t* __restrict__ key, int* __restrict__ rank, int n) {
  __shared__ uint64_t kt[JT];
  int i = blockIdx.x * RB + threadIdx.x;
  uint64_t ki = key[i];
  int jbase = blockIdx.y * JT;
  for (int t = threadIdx.x; t < JT; t += RB) kt[t] = key[jbase + t];
  __syncthreads();
  int cnt = 0;
  #pragma unroll 8
  for (int jj = 0; jj < JT; ++jj) {
    cnt += (kt[jj] < ki) ? 1 : 0;
  }
  atomicAdd(&rank[i], cnt);
}

// rank[k] == inv[k] (sorted position of element k). Build:
//   pe[rank[k]].x = e[k]            (e_sorted scatter)
//   pe[k].y      = ev[rank[k]]      (reference's inverse-perm side reorder)
//   th_s[k]      = theta[rank[k]]
__global__ void scatter_kernel(const float* __restrict__ e,
                               const int* __restrict__ rank,
                               const int* __restrict__ ev,
                               const float* __restrict__ theta,
                               float2* __restrict__ pe,
                               float* __restrict__ th_s, int n) {
  int k = blockIdx.x * blockDim.x + threadIdx.x;
  if (k < n) {
    int r = rank[k];
    ((float*)&pe[r])[0] = e[k];          // .x — scatter (distinct dword, no race)
    ((float*)&pe[k])[1] = (float)ev[r];  // .y — gather
    th_s[k] = theta[r];
  }
}

// ---------------------------------------------------------------------------
// Main O(n^2) kernel: ROWS rows per block, 2 j's per float4 load, 1-deep
// register prefetch. pdf = exp2(c*d^2); cdf via A&S 7.1.26 erf reusing the
// same exponential. exp/rcp ride the quarter-rate trans pipe.
// ---------------------------------------------------------------------------
__global__ __launch_bounds__(RB) void row_kernel(
    const float2* __restrict__ pe, const float* __restrict__ th_s,
    float* __restrict__ out, int n) {
  const int row0 = blockIdx.x * ROWS;

  float ei[ROWS], sumE[ROWS], sc[ROWS];
  #pragma unroll
  for (int r = 0; r < ROWS; ++r) {
    ei[r] = pe[row0 + r].x;     // block-uniform -> scalar load
    sumE[r] = 0.0f;
    sc[r] = 0.0f;
  }

  const float P2 = 0.23164390f;          // 0.3275911 / sqrt(2)
  const float NEG_HALF_LOG2E = -0.72134752044f;  // -0.5 * log2(e)

  const float4* pe4 = (const float4*)pe;
  const int it_count = n / (2 * RB);     // 16 for n=8192
  float4 q = pe4[threadIdx.x];

  for (int it = 0; it < it_count; ++it) {
    float4 qn = pe4[(it + 1) * RB + threadIdx.x];  // prefetch (padded tail)
    #pragma unroll
    for (int half = 0; half < 2; ++half) {
      float ej  = half ? q.z : q.x;
      float evj = half ? q.w : q.y;
      #pragma unroll
      for (int r = 0; r < ROWS; ++r) {
        float d = ei[r] - ej;
        float g = __builtin_amdgcn_exp2f(d * d * NEG_HALF_LOG2E); // exp(-d^2/2)
        sumE[r] = fmaf(g, evj, sumE[r]);
        // t = 1/(1 + p*|d|/sqrt2) — abs folds into the VOP3 modifier
        float t = __builtin_amdgcn_rcpf(fmaf(P2, __builtin_fabsf(d), 1.0f));
        float poly = t * (0.254829592f +
                     t * (-0.284496736f +
                     t * (1.421413741f +
                     t * (-1.453152027f +
                     t * 1.061405429f))));
        float erfa = fmaf(-poly, g, 1.0f);        // erf(|d|/sqrt2)
        sc[r] += __builtin_copysignf(erfa, d);    // sum sign*erf; +0.5n later
      }
    }
    q = qn;
  }

  // per-wave shuffle reduction
  #pragma unroll
  for (int r = 0; r < ROWS; ++r) {
    #pragma unroll
    for (int off = 32; off > 0; off >>= 1) {
      sumE[r] += __shfl_down(sumE[r], off, 64);
      sc[r]   += __shfl_down(sc[r], off, 64);
    }
  }

  __shared__ float red[RB / 64][ROWS][2];
  __shared__ float termbuf[ROWS];
  const int wave = threadIdx.x >> 6;
  const int lane = threadIdx.x & 63;
  if (lane == 0) {
    #pragma unroll
    for (int r = 0; r < ROWS; ++r) {
      red[wave][r][0] = sumE[r];
      red[wave][r][1] = sc[r];
    }
  }
  __syncthreads();

  if (threadIdx.x < ROWS) {
    const int r = threadIdx.x;
    float tE = 0.0f, tS = 0.0f;
    #pragma unroll
    for (int w = 0; w < RB / 64; ++w) { tE += red[w][r][0]; tS += red[w][r][1]; }
    const float fn = (float)n;
    const float inv_sqrt_2pi = 0.39894228040143267794f;
    float condE = tE * inv_sqrt_2pi / fn + fn * 1e-32f;
    float surv  = (0.5f * fn + 0.5f * tS) / fn;   // sum cdf / n
    const int i = row0 + r;
    float evi = pe[i].y;
    termbuf[r] = (__logf(condE) - __logf(surv) + th_s[i]) * evi;
  }
  __syncthreads();

  if (threadIdx.x == 0) {   // one atomic per block
    float s = 0.0f;
    #pragma unroll
    for (int r = 0; r < ROWS; ++r) s += termbuf[r];
    atomicAdd(out, -s / (float)n);
  }
}

extern "C" void kernel_launch(void* const* d_in, const int* in_sizes, int n_in,
                              void* d_out, int out_size, void* d_ws, size_t ws_size,
                              hipStream_t stream) {
  const float* theta = (const float*)d_in[0];   // log_h (n,1) fp32
  const float* dur   = (const float*)d_in[1];   // durations (n,) fp32
  const int*   ev    = (const int*)d_in[2];     // events (n,) int32
  float* out = (float*)d_out;
  const int n = in_sizes[1];

  // workspace layout (8-byte aligned first); pe padded by 2*RB float2 for the
  // float4 prefetch tail (values never used in arithmetic).
  char* ws = (char*)d_ws;
  uint64_t* key   = (uint64_t*)ws;  ws += n * sizeof(uint64_t);
  float2*   pe    = (float2*)ws;    ws += (n + 2 * RB) * sizeof(float2);
  float*    e     = (float*)ws;     ws += n * sizeof(float);
  int*      rank  = (int*)ws;       ws += n * sizeof(int);
  float*    th_s  = (float*)ws;     ws += n * sizeof(float);

  hipMemsetAsync(d_out, 0, out_size * sizeof(float), stream);

  int nb = (n + RB - 1) / RB;
  prep_kernel<<<nb, RB, 0, stream>>>(theta, dur, e, key, rank, n);
  rank_kernel<<<dim3(n / RB, n / JT), RB, 0, stream>>>(key, rank, n);
  scatter_kernel<<<nb, RB, 0, stream>>>(e, rank, ev, theta, pe, th_s, n);
  row_kernel<<<n / ROWS, RB, 0, stream>>>(pe, th_s, out, n);
}